// Round 7
// baseline (240.839 us; speedup 1.0000x reference)
//
#include <hip/hip_runtime.h>

// PsRoiOffset, round 7: ws-preconverted bf16 features + weights; one wave
// per (roi,bin) site; MFMA A-operands loaded directly from cache (no LDS
// staging, no f2bf in the hot loop, no cross-wave reduction).
//
// features (1,200,304,196) f32, rois (512,4) f32,
// W_off (3,3,196,392) f32, b_off (392) f32, out (512,7,7,4) f32.
//
// ws layout: [0 .. ) bf16 feature map [H][W][224] (196 ch + 28 zero pad)
//            [F ..)  bf16 weights [49][9][8][224]  (B^T per bin/tap, padded)
// Fallback (ws too small): round-6 union kernel reading fp32 directly.

constexpr int H = 200, W = 304, C = 196, CO = 392;
constexpr int KK = 7, DIM = 4, NROI = 512;
constexpr int KW = 224;                       // padded K
constexpr int KP = 232;                       // fallback A row stride
constexpr size_t F_ELEMS = (size_t)H * W * KW;            // bf16 elems
constexpr size_t W_ELEMS = (size_t)49 * 9 * 8 * KW;
constexpr size_t WS_NEED = (F_ELEMS + W_ELEMS) * 2;       // ~28.8 MB

typedef __attribute__((ext_vector_type(8))) short bf16x8;
typedef __attribute__((ext_vector_type(4))) float f32x4;

static __device__ inline unsigned short f2bf(float x) {
  unsigned int u = __float_as_uint(x);
  return (unsigned short)((u + 0x7FFFu + ((u >> 16) & 1u)) >> 16);
}

static __device__ inline void roi_geom(const float* __restrict__ rois, int n,
                                       int bi, int bj,
                                       int* ycand, int* xcand,
                                       float* wy, float* wx) {
  const float rx1 = rois[n * 4 + 0] * 0.25f;
  const float ry1 = rois[n * 4 + 1] * 0.25f;
  const float rx2 = rois[n * 4 + 2] * 0.25f;
  const float ry2 = rois[n * 4 + 3] * 0.25f;
  const float bh = (ry2 - ry1) * (1.0f / 7.0f);
  const float bw = (rx2 - rx1) * (1.0f / 7.0f);
#pragma unroll
  for (int si = 0; si < 2; ++si) {
    float sy = ry1 + ((float)bi + ((float)si + 0.5f) * 0.5f) * bh;
    sy = fminf(fmaxf(sy, 0.0f), (float)(H - 1));
    float fy = floorf(sy);
    wy[si] = sy - fy;
    int i0 = (int)fy;
    ycand[2 * si] = i0;
    ycand[2 * si + 1] = min(i0 + 1, H - 1);

    float sx = rx1 + ((float)bj + ((float)si + 0.5f) * 0.5f) * bw;
    sx = fminf(fmaxf(sx, 0.0f), (float)(W - 1));
    float fx = floorf(sx);
    wx[si] = sx - fx;
    int j0 = (int)fx;
    xcand[2 * si] = j0;
    xcand[2 * si + 1] = min(j0 + 1, W - 1);
  }
}

// ---- prep 1: features f32 [H][W][196] -> ws bf16 [H][W][224] ----
__global__ __launch_bounds__(256) void fprep_kernel(
    const float* __restrict__ feat, unsigned short* __restrict__ fbf)
{
  const long long u = (long long)blockIdx.x * 256 + threadIdx.x;
  const long long TOT = (long long)H * W * (KW / 4);
  if (u >= TOT) return;
  const int k4 = (int)(u % (KW / 4));
  const long long pix = u / (KW / 4);
  const int k = k4 * 4;
  ushort4 v = make_ushort4(0, 0, 0, 0);
  const float* src = feat + pix * C;
#pragma unroll
  for (int j = 0; j < 4; ++j)
    if (k + j < C) ((unsigned short*)&v)[j] = f2bf(src[k + j]);
  *reinterpret_cast<ushort4*>(fbf + pix * KW + k) = v;
}

// ---- prep 2: W_off (3,3,196,392) f32 -> ws bf16 [49][9][8][224] ----
__global__ __launch_bounds__(256) void wprep_kernel(
    const float* __restrict__ Woff, unsigned short* __restrict__ wbf)
{
  const int u = blockIdx.x * 256 + threadIdx.x;
  const int TOT = 49 * 9 * 8 * (KW / 4);
  if (u >= TOT) return;
  const int k4 = u % (KW / 4);
  const int n  = (u / (KW / 4)) % 8;
  const int p  = (u / (KW / 4 * 8)) % 9;
  const int g  = u / (KW / 4 * 8 * 9);
  const int k  = k4 * 4;
  ushort4 v = make_ushort4(0, 0, 0, 0);
  const int o = g * 8 + n;
#pragma unroll
  for (int j = 0; j < 4; ++j)
    if (k + j < C)
      ((unsigned short*)&v)[j] = f2bf(Woff[(size_t)(p * C + k + j) * CO + o]);
  *reinterpret_cast<ushort4*>(wbf + ((size_t)(g * 9 + p) * 8 + n) * KW + k) = v;
}

// ---- main: one wave per (roi, bin) ----
__global__ __launch_bounds__(256) void psroi_direct_kernel(
    const float* __restrict__ feat, const float* __restrict__ rois,
    const unsigned short* __restrict__ fbf,
    const unsigned short* __restrict__ wbf,
    const float* __restrict__ boff, float* __restrict__ out)
{
  // bijective XCD swizzle over 6272 blocks (6272 % 8 == 0)
  const int bid = blockIdx.x;
  const int wid = (bid & 7) * (49 * NROI / 4 / 8) + (bid >> 3);
  const int wv = threadIdx.x >> 6;
  const int lane = threadIdx.x & 63;
  const int site = wid * 4 + wv;           // 0..25087
  const int n = site / 49, g = site % 49;
  const int bi = g / KK, bj = g % KK;
  const int m_lane = lane & 15;
  const int k_hi = lane >> 4;

  __shared__ float Cw[4][16][9];           // per-wave C exchange, 2304 B

  int yc4[4], xc4[4];
  float wy2[2], wx2[2];
  roi_geom(rois, n, bi, bj, yc4, xc4, wy2, wx2);

  // this lane's corner for A rows
  const int ycc = yc4[m_lane >> 2];
  const int xcc = xc4[m_lane & 3];

  f32x4 acc = {0.f, 0.f, 0.f, 0.f};

#pragma unroll 1
  for (int p = 0; p < 9; ++p) {
    const int dy = p / 3 - 1, dx = p % 3 - 1;
    const int ys = ycc + dy, xs = xcc + dx;
    const bool valid = (ys >= 0) && (ys < H) && (xs >= 0) && (xs < W);
    const unsigned short* arow = fbf + (size_t)(ys * W + xs) * KW + k_hi * 8;
    const unsigned short* brow =
        wbf + ((size_t)(g * 9 + p) * 8 + m_lane) * KW + k_hi * 8;
    const bool bval = (m_lane < 8);
#pragma unroll
    for (int ks = 0; ks < 7; ++ks) {
      bf16x8 a = (bf16x8)(short)0;
      if (valid) a = *reinterpret_cast<const bf16x8*>(arow + ks * 32);
      bf16x8 b = (bf16x8)(short)0;
      if (bval) b = *reinterpret_cast<const bf16x8*>(brow + ks * 32);
      acc = __builtin_amdgcn_mfma_f32_16x16x32_bf16(a, b, acc, 0, 0, 0);
    }
  }

  // C exchange within the wave: lane holds C[k_hi*4+r][m_lane]
  if (m_lane < 8) {
#pragma unroll
    for (int r = 0; r < 4; ++r)
      Cw[wv][k_hi * 4 + r][m_lane] = acc[r];
  }
  __syncthreads();

  // ---- epilogue: lane = (corner, d); fp32 bilinear; shuffle-combine ----
  {
    const int corner = lane >> 2;
    const int d = lane & 3;
    const int yc = yc4[corner >> 2];
    const int xc = xc4[corner & 3];
    const int c = g * DIM + d;

    const float offy = Cw[wv][corner][2 * d]     + boff[2 * c];
    const float offx = Cw[wv][corner][2 * d + 1] + boff[2 * c + 1];

    float yy = fminf(fmaxf((float)yc + offy, 0.0f), (float)(H - 1));
    float xx = fminf(fmaxf((float)xc + offx, 0.0f), (float)(W - 1));
    const float fy = floorf(yy), fx = floorf(xx);
    const float ay = yy - fy, ax = xx - fx;
    const int iy0 = (int)fy, ix0 = (int)fx;
    const int iy1 = min(iy0 + 1, H - 1), ix1 = min(ix0 + 1, W - 1);
    const float v00 = feat[(size_t)(iy0 * W + ix0) * C + c];
    const float v01 = feat[(size_t)(iy0 * W + ix1) * C + c];
    const float v10 = feat[(size_t)(iy1 * W + ix0) * C + c];
    const float v11 = feat[(size_t)(iy1 * W + ix1) * C + c];
    const float top = v00 + (v01 - v00) * ax;
    const float bot = v10 + (v11 - v10) * ax;
    const float om = top + (bot - top) * ay;

    const int yci = corner >> 2, xci = corner & 3;
    const int si = yci >> 1, a = yci & 1;
    const int sj = xci >> 1, b = xci & 1;
    const float cy = a ? wy2[si] : 1.0f - wy2[si];
    const float cx = b ? wx2[sj] : 1.0f - wx2[sj];
    float v = 0.25f * cy * cx * om;

    v += __shfl_xor(v, 4);
    v += __shfl_xor(v, 8);
    v += __shfl_xor(v, 16);
    v += __shfl_xor(v, 32);

    if (lane < 4)
      out[(size_t)n * (KK * KK * DIM) + g * DIM + lane] = v;
  }
}

// ---- fallback (ws too small): round-6 union kernel, fp32 inputs ----
__global__ __launch_bounds__(256) void psroi_union_kernel(
    const float* __restrict__ feat, const float* __restrict__ rois,
    const float* __restrict__ Woff, const float* __restrict__ boff,
    float* __restrict__ out)
{
  const int bid = blockIdx.x;
  const int wid = (bid & 7) * (49 * NROI / 8) + (bid >> 3);
  const int g = wid % 49;
  const int n = wid / 49;
  const int bi = g / KK, bj = g % KK;
  const int tid = threadIdx.x;
  const int lane = tid & 63;
  const int wv = tid >> 6;
  const int m_lane = lane & 15;
  const int k_hi = lane >> 4;

  __shared__ short Abuf[64 * KP];
  __shared__ float Cbuf[4 * 16 * 9];

  for (int i = tid; i < 64 * (KP - C); i += 256) {
    const int row = i / (KP - C), col = C + i % (KP - C);
    Abuf[row * KP + col] = 0;
  }

  int yc4[4], xc4[4];
  float wy2[2], wx2[2];
  roi_geom(rois, n, bi, bj, yc4, xc4, wy2, wx2);

  {
    const int pos = tid >> 2;
    const int yi = pos >> 3, xi = pos & 7;
    const int yrow = (yi < 4) ? (yc4[0] + yi - 1) : (yc4[2] + yi - 5);
    const int xcol = (xi < 4) ? (xc4[0] + xi - 1) : (xc4[2] + xi - 5);
    const bool valid = (yrow >= 0) && (yrow < H) && (xcol >= 0) && (xcol < W);
    const float* frow = feat + (size_t)(yrow * W + xcol) * C;
    short* arow = &Abuf[pos * KP];
    const int l = tid & 3;
#pragma unroll
    for (int k = 0; k <= 12; ++k) {
      const int c = l + 4 * k;
      if (c < 49) {
        ushort4 v = make_ushort4(0, 0, 0, 0);
        if (valid) {
          const float4 f4 = *reinterpret_cast<const float4*>(frow + 4 * c);
          v.x = f2bf(f4.x); v.y = f2bf(f4.y);
          v.z = f2bf(f4.z); v.w = f2bf(f4.w);
        }
        *reinterpret_cast<ushort4*>(arow + 4 * c) = v;
      }
    }
  }
  __syncthreads();

  const int i0 = m_lane >> 2, j0 = m_lane & 3;
  const int dyA = yc4[1] - yc4[0], dyB = yc4[3] - yc4[2];
  const int dxA = xc4[1] - xc4[0], dxB = xc4[3] - xc4[2];
  int ybase = (i0 & 2) ? 5 : 1;
  ybase += (i0 & 1) ? ((i0 & 2) ? dyB : dyA) : 0;
  int xbase = (j0 & 2) ? 5 : 1;
  xbase += (j0 & 1) ? ((j0 & 2) ? dxB : dxA) : 0;

  f32x4 acc = {0.f, 0.f, 0.f, 0.f};

#pragma unroll 1
  for (int p = wv; p < 9; p += 4) {
    bf16x8 bfr[7];
#pragma unroll
    for (int ks = 0; ks < 7; ++ks) bfr[ks] = (bf16x8)(short)0;
    if (m_lane < 8) {
#pragma unroll
      for (int ks = 0; ks < 7; ++ks) {
        bf16x8 b = (bf16x8)(short)0;
#pragma unroll
        for (int j = 0; j < 8; ++j) {
          const int k = ks * 32 + k_hi * 8 + j;
          if (k < C)
            b[j] = (short)f2bf(Woff[(size_t)(p * C + k) * CO + g * 8 + m_lane]);
        }
        bfr[ks] = b;
      }
    }
    const int row = (ybase + p / 3 - 1) * 8 + (xbase + p % 3 - 1);
    const short* arow = &Abuf[row * KP];
#pragma unroll
    for (int ks = 0; ks < 7; ++ks) {
      const bf16x8 a = *reinterpret_cast<const bf16x8*>(arow + ks * 32 + k_hi * 8);
      acc = __builtin_amdgcn_mfma_f32_16x16x32_bf16(a, bfr[ks], acc, 0, 0, 0);
    }
  }

  if (m_lane < 8) {
#pragma unroll
    for (int r = 0; r < 4; ++r)
      Cbuf[(wv * 16 + k_hi * 4 + r) * 9 + m_lane] = acc[r];
  }
  __syncthreads();

  if (tid < 64) {
    const int corner = tid >> 2;
    const int d = tid & 3;
    const int yc = yc4[corner >> 2];
    const int xc = xc4[corner & 3];
    const int c = g * DIM + d;

    float offy = boff[2 * c], offx = boff[2 * c + 1];
#pragma unroll
    for (int w = 0; w < 4; ++w) {
      offy += Cbuf[(w * 16 + corner) * 9 + 2 * d];
      offx += Cbuf[(w * 16 + corner) * 9 + 2 * d + 1];
    }

    float yy = fminf(fmaxf((float)yc + offy, 0.0f), (float)(H - 1));
    float xx = fminf(fmaxf((float)xc + offx, 0.0f), (float)(W - 1));
    const float fy = floorf(yy), fx = floorf(xx);
    const float ay = yy - fy, ax = xx - fx;
    const int iy0 = (int)fy, ix0 = (int)fx;
    const int iy1 = min(iy0 + 1, H - 1), ix1 = min(ix0 + 1, W - 1);
    const float v00 = feat[(size_t)(iy0 * W + ix0) * C + c];
    const float v01 = feat[(size_t)(iy0 * W + ix1) * C + c];
    const float v10 = feat[(size_t)(iy1 * W + ix0) * C + c];
    const float v11 = feat[(size_t)(iy1 * W + ix1) * C + c];
    const float top = v00 + (v01 - v00) * ax;
    const float bot = v10 + (v11 - v10) * ax;
    const float om = top + (bot - top) * ay;

    const int yci = corner >> 2, xci = corner & 3;
    const int si = yci >> 1, a = yci & 1;
    const int sj = xci >> 1, b = xci & 1;
    const float cy = a ? wy2[si] : 1.0f - wy2[si];
    const float cx = b ? wx2[sj] : 1.0f - wx2[sj];
    float v = 0.25f * cy * cx * om;

    v += __shfl_xor(v, 4);
    v += __shfl_xor(v, 8);
    v += __shfl_xor(v, 16);
    v += __shfl_xor(v, 32);

    if (tid < 4)
      out[(size_t)n * (KK * KK * DIM) + g * DIM + tid] = v;
  }
}

extern "C" void kernel_launch(void* const* d_in, const int* in_sizes, int n_in,
                              void* d_out, int out_size, void* d_ws, size_t ws_size,
                              hipStream_t stream) {
  const float* feat = (const float*)d_in[0];
  const float* rois = (const float*)d_in[1];
  const float* Woff = (const float*)d_in[2];
  const float* boff = (const float*)d_in[3];
  float* out = (float*)d_out;

  if (ws_size >= WS_NEED) {
    unsigned short* fbf = (unsigned short*)d_ws;
    unsigned short* wbf = fbf + F_ELEMS;
    const long long ftot = (long long)H * W * (KW / 4);
    fprep_kernel<<<dim3((unsigned)((ftot + 255) / 256)), dim3(256), 0, stream>>>(
        feat, fbf);
    const int wtot = 49 * 9 * 8 * (KW / 4);
    wprep_kernel<<<dim3((wtot + 255) / 256), dim3(256), 0, stream>>>(Woff, wbf);
    psroi_direct_kernel<<<dim3(49 * NROI / 4), dim3(256), 0, stream>>>(
        feat, rois, fbf, wbf, boff, out);
  } else {
    psroi_union_kernel<<<dim3(49 * NROI), dim3(256), 0, stream>>>(
        feat, rois, Woff, boff, out);
  }
}